// Round 9
// baseline (526.079 us; speedup 1.0000x reference)
//
#include <hip/hip_runtime.h>
#include <math.h>

#define NB 8
#define NN 1024
#define DD 512

typedef unsigned short u16;
typedef unsigned int u32;
typedef unsigned long long u64;
typedef __attribute__((ext_vector_type(8))) short bfrag;
typedef __attribute__((ext_vector_type(4))) float ffrag;

__device__ __forceinline__ u16 f2b(float f) {
    union { float f; u32 u; } v; v.f = f;
    u32 r = v.u + 0x7fffu + ((v.u >> 16) & 1u);   // RNE
    return (u16)(r >> 16);
}
__device__ __forceinline__ float b2f(u16 b) {
    union { u32 u; float f; } v; v.u = ((u32)b) << 16;
    return v.f;
}

// A&S 7.1.26 erf: |err| <= 1.5e-7
__device__ __forceinline__ float gelu_cheap(float v) {
    float s = v * 0.70710678118654752f;
    float a = fabsf(s);
    float t = 1.0f / (1.0f + 0.3275911f * a);
    float p = ((((1.061405429f * t - 1.453152027f) * t + 1.421413741f) * t
                - 0.284496736f) * t + 0.254829592f) * t;
    float erfa = 1.0f - p * __expf(-a * a);
    float erfs = copysignf(erfa, s);
    return 0.5f * v * (1.0f + erfs);
}

// async global->LDS, 16B per lane; lds base must be wave-uniform
__device__ __forceinline__ void gload_lds16(const void* g, void* l) {
    __builtin_amdgcn_global_load_lds(
        (const __attribute__((address_space(1))) void*)g,
        (__attribute__((address_space(3))) void*)l, 16, 0, 0);
}

// ---------------- shared transpose body: fp32 [R][C] tile -> bf16 [C][R] ---------
__device__ __forceinline__ void tcvt_body(
    const float* __restrict__ in, u16* __restrict__ out,
    int R, int C, int r0, int c0, int t, float tile[32][33])
{
    int tr = t >> 3, tc = (t & 7) * 4;
    float4 v = *(const float4*)(in + (size_t)(r0 + tr) * C + c0 + tc);
    tile[tr][tc + 0] = v.x; tile[tr][tc + 1] = v.y;
    tile[tr][tc + 2] = v.z; tile[tr][tc + 3] = v.w;
    __syncthreads();
    u32 w0 = (u32)f2b(tile[tc + 0][tr]) | ((u32)f2b(tile[tc + 1][tr]) << 16);
    u32 w1 = (u32)f2b(tile[tc + 2][tr]) | ((u32)f2b(tile[tc + 3][tr]) << 16);
    uint2 wv; wv.x = w0; wv.y = w1;
    *(uint2*)(out + (size_t)(c0 + tr) * R + r0 + tc) = wv;
}

// ---------------- per-layer transpose + cvt: x fp32 [1024][512] -> xT bf16 -------
__global__ __launch_bounds__(256) void transpose_cvt(
    const float* __restrict__ in, u16* __restrict__ out,
    int R, int C, size_t inStr, size_t outStr)
{
    __shared__ float tile[32][33];
    int z = blockIdx.z;
    tcvt_body(in + inStr * z, out + outStr * z,
              R, C, blockIdx.y * 32, blockIdx.x * 32, threadIdx.x, tile);
}

// ---------------- fused prep: mask_pack + score_proj(l0) + transpose(nf->xT) -----
// flat grid 6656 blocks: [0,512) mask | [512,2560) score | [2560,6656) nf-transpose
__global__ __launch_bounds__(256) void prep_fused(
    const int* __restrict__ adj, u64* __restrict__ mb,
    const float* __restrict__ nf, const float* __restrict__ attn_w,
    float* __restrict__ si, float* __restrict__ sj, u16* __restrict__ xT)
{
    __shared__ float tile[32][33];
    int bid = blockIdx.x;
    int tid = threadIdx.x;
    if (bid < 512) {
        // ---- mask pack: adj + diag -> bitmask [B*N][16] u64 ----
        int idx = bid * 256 + tid;
        int w = idx & 15;
        int bi = idx >> 4;
        int i = bi & 1023;
        const int4* p = (const int4*)(adj + (size_t)bi * NN + w * 64);
        u64 m = 0;
#pragma unroll
        for (int q = 0; q < 16; ++q) {
            int4 v = p[q];
            if (v.x > 0) m |= 1ull << (q * 4 + 0);
            if (v.y > 0) m |= 1ull << (q * 4 + 1);
            if (v.z > 0) m |= 1ull << (q * 4 + 2);
            if (v.w > 0) m |= 1ull << (q * 4 + 3);
        }
        if (w == (i >> 6)) m |= 1ull << (i & 63);
        mb[idx] = m;
    } else if (bid < 2560) {
        // ---- score projection for layer 0 ----
        int wave = tid >> 6;
        int lane = tid & 63;
        int row = (bid - 512) * 4 + wave;
        const float4* xr = (const float4*)(nf + (size_t)row * DD) + lane * 2;
        const float4* w1 = (const float4*)(attn_w) + lane * 2;
        const float4* w2 = (const float4*)(attn_w + DD) + lane * 2;
        float a = 0.f, b2 = 0.f;
#pragma unroll
        for (int c = 0; c < 2; ++c) {
            float4 xv = xr[c], wa = w1[c], wb = w2[c];
            a  += xv.x * wa.x + xv.y * wa.y + xv.z * wa.z + xv.w * wa.w;
            b2 += xv.x * wb.x + xv.y * wb.y + xv.z * wb.z + xv.w * wb.w;
        }
#pragma unroll
        for (int off = 32; off > 0; off >>= 1) {
            a  += __shfl_xor(a, off);
            b2 += __shfl_xor(b2, off);
        }
        if (lane == 0) { si[row] = a; sj[row] = b2; }
    } else {
        // ---- transpose nf -> xT (layer 0): 8 batches of [1024][512] -> [512][1024]
        int q = bid - 2560;               // 0..4095
        int bx = q & 15, by = (q >> 4) & 31, bz = q >> 9;
        tcvt_body(nf + (size_t)bz * NN * DD, xT + (size_t)bz * NN * DD,
                  1024, 512, by * 32, bx * 32, tid, tile);
    }
}

// ---------------- weight transposes, both in one dispatch ------------------------
// grid (64,16,6): z<3 -> W1 layer z [512][2048]->[2048][512]; z>=3 -> W2 layer z-3
__global__ __launch_bounds__(256) void trans_w(
    const float* __restrict__ W1, const float* __restrict__ W2,
    u16* __restrict__ W1t, u16* __restrict__ W2t)
{
    __shared__ float tile[32][33];
    int z = blockIdx.z;
    int bx = blockIdx.x, by = blockIdx.y;
    if (z < 3) {
        tcvt_body(W1 + (size_t)z * 512 * 2048, W1t + (size_t)z * 1048576,
                  512, 2048, by * 32, bx * 32, threadIdx.x, tile);
    } else {
        int q = by * 64 + bx;             // 0..1023
        int bx2 = q & 15, by2 = q >> 4;   // (16, 64)
        tcvt_body(W2 + (size_t)(z - 3) * 2048 * 512, W2t + (size_t)(z - 3) * 1048576,
                  2048, 512, by2 * 32, bx2 * 32, threadIdx.x, tile);
    }
}

// ============ FUSED softmax + agg GEMM: 64x128 tile, K=1024 ======================
// Each block owns 64 COMPLETE score rows -> softmax lives inside:
//   prologue: stage sj (4KB) + mask rows (8KB) in LDS; 2 register passes
//   (max, sum-of-exp) with 4-lane shuffle reduces; stats stay in registers.
//   K-loop: COMPUTE the 64x64 P-subtile (p = exp(s-mx)*inv, bit-identical to the
//   old softmax_p values) and ds_write it into the same swizzled LDS image the
//   MFMA reader expects; B (xT) keeps the counted-vmcnt double-buffer pipeline.
// Removes: softmax_p kernel + 16MB P write + P re-read per layer.
// LDS: B dbuf 32KB + A 8KB + sj 4KB + mask 8KB = 52KB -> 3 blocks/CU.
__global__ __launch_bounds__(256) void agg_fused(
    const float* __restrict__ si, const float* __restrict__ sj,
    const float* __restrict__ attn_b, const u64* __restrict__ mb,
    const u16* __restrict__ xT, const float* __restrict__ xres,
    float* __restrict__ hres)
{
    __shared__ __align__(16) u16 ldsB[16384];   // 2 x (128 x 64) bf16
    __shared__ __align__(16) u16 ldsA[4096];    // 64 x 64 bf16 (swizzled image)
    __shared__ __align__(16) float sjl[1024];
    __shared__ __align__(16) u64 ml[1024];      // 64 rows x 16 words

    // XCD-chunked swizzle over 512 blocks (grid 4,16,8)
    int gx = gridDim.x, gy = gridDim.y;
    int wg = blockIdx.x + gx * (blockIdx.y + gy * blockIdx.z);
    int nwg = gx * gy * gridDim.z;
    wg = (wg & 7) * (nwg >> 3) + (wg >> 3);
    int z = wg / (gx * gy);
    int rem = wg - z * (gx * gy);
    int by = rem / gx, bx = rem - by * gx;
    int m0 = by * 64, n0 = bx * 128;
    int tid = threadIdx.x;
    int lane = tid & 63, wv = tid >> 6;

    // B staging addrs: tile 128 d-rows x 64 j, source xT[z][d][j], ldb = NN
    const u16* bg[4];
    u32 lbB[4];                                  // byte offsets into a B buffer
#pragma unroll
    for (int i = 0; i < 4; ++i) {
        int q = i * 256 + tid;
        int row = q >> 3, c = q & 7;
        bg[i] = xT + (size_t)z * DD * NN + (size_t)(n0 + row) * NN + (c ^ (row & 7)) * 8;
        lbB[i] = i * 4096 + wv * 1024;
    }

    // prologue: stage sj row-vector, mask rows, and B(0)
    gload_lds16((const char*)(sj + (size_t)z * NN) + (size_t)tid * 16,
                (char*)sjl + wv * 1024);
    {
        const char* mg = (const char*)(mb + ((size_t)z * NN + m0) * 16);
#pragma unroll
        for (int i = 0; i < 2; ++i)
            gload_lds16(mg + (size_t)(i * 256 + tid) * 16,
                        (char*)ml + i * 4096 + wv * 1024);
    }
#pragma unroll
    for (int i = 0; i < 4; ++i)
        gload_lds16(bg[i], (char*)ldsB + lbB[i]);
    asm volatile("s_waitcnt vmcnt(0)" ::: "memory");
    __syncthreads();

    // ---- softmax stats: row = tid>>2, quarter = tid&3 scans 256 j ----
    float bb = attn_b[0];
    int prow = tid >> 2, pq = tid & 3;
    float siv = si[(size_t)z * NN + m0 + prow];
    const u64* mrow = &ml[prow * 16];
    float mx = -INFINITY;
#pragma unroll
    for (int g = 0; g < 4; ++g) {
        u64 w = mrow[pq * 4 + g];
        const float4* s4 = (const float4*)(sjl + pq * 256 + g * 64);
#pragma unroll 4
        for (int k = 0; k < 16; ++k) {
            float4 v = s4[k];
            float s0 = siv + v.x + bb; s0 = s0 >= 0.f ? s0 : 0.2f * s0;
            float s1 = siv + v.y + bb; s1 = s1 >= 0.f ? s1 : 0.2f * s1;
            float s2 = siv + v.z + bb; s2 = s2 >= 0.f ? s2 : 0.2f * s2;
            float s3 = siv + v.w + bb; s3 = s3 >= 0.f ? s3 : 0.2f * s3;
            int b0 = k * 4;
            if (!((w >> (b0 + 0)) & 1ull)) s0 = -INFINITY;
            if (!((w >> (b0 + 1)) & 1ull)) s1 = -INFINITY;
            if (!((w >> (b0 + 2)) & 1ull)) s2 = -INFINITY;
            if (!((w >> (b0 + 3)) & 1ull)) s3 = -INFINITY;
            mx = fmaxf(mx, fmaxf(fmaxf(s0, s1), fmaxf(s2, s3)));
        }
    }
    mx = fmaxf(mx, __shfl_xor(mx, 1));
    mx = fmaxf(mx, __shfl_xor(mx, 2));
    float sum = 0.f;
#pragma unroll
    for (int g = 0; g < 4; ++g) {
        u64 w = mrow[pq * 4 + g];
        const float4* s4 = (const float4*)(sjl + pq * 256 + g * 64);
#pragma unroll 4
        for (int k = 0; k < 16; ++k) {
            float4 v = s4[k];
            float s0 = siv + v.x + bb; s0 = s0 >= 0.f ? s0 : 0.2f * s0;
            float s1 = siv + v.y + bb; s1 = s1 >= 0.f ? s1 : 0.2f * s1;
            float s2 = siv + v.z + bb; s2 = s2 >= 0.f ? s2 : 0.2f * s2;
            float s3 = siv + v.w + bb; s3 = s3 >= 0.f ? s3 : 0.2f * s3;
            int b0 = k * 4;
            if (!((w >> (b0 + 0)) & 1ull)) s0 = -INFINITY;
            if (!((w >> (b0 + 1)) & 1ull)) s1 = -INFINITY;
            if (!((w >> (b0 + 2)) & 1ull)) s2 = -INFINITY;
            if (!((w >> (b0 + 3)) & 1ull)) s3 = -INFINITY;
            sum += __expf(s0 - mx) + __expf(s1 - mx)
                 + __expf(s2 - mx) + __expf(s3 - mx);
        }
    }
    sum += __shfl_xor(sum, 1);
    sum += __shfl_xor(sum, 2);
    float inv = 1.f / sum;

    // ---- MFMA geometry ----
    int mw = (wv >> 1) * 32, nw = (wv & 1) * 64;
    int lr = lane & 15, lq = lane >> 4;
    int sw = lr & 7;
    int rsw7 = prow & 7;
    int jj16 = pq * 16;
    u32* a32 = (u32*)ldsA;

    ffrag acc[2][4];
#pragma unroll
    for (int i = 0; i < 2; ++i)
#pragma unroll
        for (int j = 0; j < 4; ++j) acc[i][j] = (ffrag){0.f, 0.f, 0.f, 0.f};

    for (int t = 0; t < 16; ++t) {
        // issue next B tile early (hides under the A-compute VALU work)
        if (t + 1 < 16) {
#pragma unroll
            for (int i = 0; i < 4; ++i)
                gload_lds16(bg[i] + (t + 1) * 64,
                            (char*)ldsB + ((t + 1) & 1) * 16384 + lbB[i]);
        }
        // compute A-subtile: 16 p-values/thread into swizzled LDS image
        {
            u64 w = mrow[t];
            const float4* s4 = (const float4*)(sjl + t * 64 + jj16);
#pragma unroll
            for (int k4 = 0; k4 < 4; ++k4) {
                float4 v = s4[k4];
                int kk = jj16 + k4 * 4;
                float s0 = siv + v.x + bb; s0 = s0 >= 0.f ? s0 : 0.2f * s0;
                float s1 = siv + v.y + bb; s1 = s1 >= 0.f ? s1 : 0.2f * s1;
                float s2 = siv + v.z + bb; s2 = s2 >= 0.f ? s2 : 0.2f * s2;
                float s3 = siv + v.w + bb; s3 = s3 >= 0.f ? s3 : 0.2f * s3;
                float p0 = ((w >> (kk + 0)) & 1ull) ? __expf(s0 - mx) * inv : 0.f;
                float p1 = ((w >> (kk + 1)) & 1ull) ? __expf(s1 - mx) * inv : 0.f;
                float p2 = ((w >> (kk + 2)) & 1ull) ? __expf(s2 - mx) * inv : 0.f;
                float p3 = ((w >> (kk + 3)) & 1ull) ? __expf(s3 - mx) * inv : 0.f;
                u32 lo = (u32)f2b(p0) | ((u32)f2b(p1) << 16);
                u32 hi = (u32)f2b(p2) | ((u32)f2b(p3) << 16);
                int off = prow * 64 + (((kk >> 3) ^ rsw7) << 3) + (kk & 7); // u16
                a32[off >> 1] = lo;
                a32[(off >> 1) + 1] = hi;
            }
        }
        if (t + 1 < 16) {
            asm volatile("s_waitcnt vmcnt(4) lgkmcnt(0)" ::: "memory");
        } else {
            asm volatile("s_waitcnt vmcnt(0) lgkmcnt(0)" ::: "memory");
        }
        asm volatile("s_barrier" ::: "memory");   // A(t) + B(t) resident

        const u16* Bb = &ldsB[(t & 1) * 8192];
#pragma unroll
        for (int h = 0; h < 2; ++h) {
            bfrag af[2], bf[4];
#pragma unroll
            for (int i = 0; i < 2; ++i)
                af[i] = *(const bfrag*)&ldsA[(mw + i * 16 + lr) * 64 + ((h * 4 + lq) ^ sw) * 8];
#pragma unroll
            for (int j = 0; j < 4; ++j)
                bf[j] = *(const bfrag*)&Bb[(nw + j * 16 + lr) * 64 + ((h * 4 + lq) ^ sw) * 8];
#pragma unroll
            for (int i = 0; i < 2; ++i)
#pragma unroll
                for (int j = 0; j < 4; ++j)
                    acc[i][j] = __builtin_amdgcn_mfma_f32_16x16x32_bf16(af[i], bf[j], acc[i][j], 0, 0, 0);
        }
        // all waves done reading ldsA / ldsB(t&1) before next iter rewrites
        asm volatile("s_waitcnt lgkmcnt(0)\ns_barrier" ::: "memory");
    }

    float* Cf = hres + (size_t)z * NN * DD;
    const float* rf = xres + (size_t)z * NN * DD;
#pragma unroll
    for (int i = 0; i < 2; ++i) {
        int row = m0 + mw + i * 16 + lq * 4;
#pragma unroll
        for (int j = 0; j < 4; ++j) {
            int col = n0 + nw + j * 16 + lr;
#pragma unroll
            for (int r = 0; r < 4; ++r) {
                size_t off = (size_t)(row + r) * DD + col;
                Cf[off] = acc[i][j][r] + rf[off];
            }
        }
    }
}

// ======================= bf16 MFMA GEMM: 64x128 tile, BK=64, LDS double-buffer ===
// AITER-style pipeline: prefetch next tile's global_load_lds, s_waitcnt vmcnt(6),
// raw s_barrier. XOR swizzle folded into global addr. T1 XCD-chunked swizzle.
// EPI: 0 = +res(fp32), fp32 out | 2 = +bias +res(bf16), fp32 out
template <int EPI>
__global__ __launch_bounds__(256) void gemm64(
    const u16* __restrict__ A, const u16* __restrict__ Bm,
    const float* __restrict__ bias, const void* __restrict__ res,
    void* __restrict__ Cout, int K, int N, int lda, int ldb,
    size_t aStr, size_t bStr, size_t cStr, size_t resStr)
{
    __shared__ __align__(16) u16 lds[24576];   // 48 KB
    int gx = gridDim.x, gy = gridDim.y;
    int wg = blockIdx.x + gx * (blockIdx.y + gy * blockIdx.z);
    int nwg = gx * gy * gridDim.z;
    wg = (wg & 7) * (nwg >> 3) + (wg >> 3);
    int z = wg / (gx * gy);
    int rem = wg - z * (gx * gy);
    int by = rem / gx, bx = rem - by * gx;
    int m0 = by * 64, n0 = bx * 128;
    int tid = threadIdx.x;
    int lane = tid & 63, wv = tid >> 6;

    const u16* ag[2]; const u16* bg[4];
    u32 la[2], lb[4];
#pragma unroll
    for (int i = 0; i < 2; ++i) {
        int q = i * 256 + tid;
        int row = q >> 3, c = q & 7;
        ag[i] = A + aStr * z + (size_t)(m0 + row) * lda + (c ^ (row & 7)) * 8;
        la[i] = i * 2048 + wv * 512;
    }
#pragma unroll
    for (int i = 0; i < 4; ++i) {
        int q = i * 256 + tid;
        int row = q >> 3, c = q & 7;
        bg[i] = Bm + bStr * z + (size_t)(n0 + row) * ldb + (c ^ (row & 7)) * 8;
        lb[i] = 8192 + i * 2048 + wv * 512;
    }

    int mw = (wv >> 1) * 32, nw = (wv & 1) * 64;
    int lr = lane & 15, lq = lane >> 4;
    int sw = lr & 7;

    ffrag acc[2][4];
#pragma unroll
    for (int i = 0; i < 2; ++i)
#pragma unroll
        for (int j = 0; j < 4; ++j) acc[i][j] = (ffrag){0.f, 0.f, 0.f, 0.f};

#pragma unroll
    for (int i = 0; i < 2; ++i) gload_lds16(ag[i], &lds[la[i]]);
#pragma unroll
    for (int i = 0; i < 4; ++i) gload_lds16(bg[i], &lds[lb[i]]);

    for (int k0 = 0; k0 < K; k0 += 64) {
        int cur = (k0 >> 6) & 1;
        if (k0 + 64 < K) {
#pragma unroll
            for (int i = 0; i < 2; ++i)
                gload_lds16(ag[i] + k0 + 64, &lds[((cur ^ 1) << 12) + la[i]]);
#pragma unroll
            for (int i = 0; i < 4; ++i)
                gload_lds16(bg[i] + k0 + 64, &lds[((cur ^ 1) << 13) + lb[i]]);
            asm volatile("s_waitcnt vmcnt(6)" ::: "memory");
        } else {
            asm volatile("s_waitcnt vmcnt(0)" ::: "memory");
        }
        asm volatile("s_barrier" ::: "memory");

        const u16* Ab = &lds[cur << 12];
        const u16* Bb = &lds[8192 + (cur << 13)];
#pragma unroll
        for (int h = 0; h < 2; ++h) {
            bfrag af[2], bf[4];
#pragma unroll
            for (int i = 0; i < 2; ++i)
                af[i] = *(const bfrag*)&Ab[(mw + i * 16 + lr) * 64 + ((h * 4 + lq) ^ sw) * 8];
#pragma unroll
            for (int j = 0; j < 4; ++j)
                bf[j] = *(const bfrag*)&Bb[(nw + j * 16 + lr) * 64 + ((h * 4 + lq) ^ sw) * 8];
#pragma unroll
            for (int i = 0; i < 2; ++i)
#pragma unroll
                for (int j = 0; j < 4; ++j)
                    acc[i][j] = __builtin_amdgcn_mfma_f32_16x16x32_bf16(af[i], bf[j], acc[i][j], 0, 0, 0);
        }
        asm volatile("s_waitcnt lgkmcnt(0)\ns_barrier" ::: "memory");
    }

    float* Cf = (float*)Cout + cStr * z;
    const float* resf = (const float*)res;
    const u16*   resb = (const u16*)res;
#pragma unroll
    for (int i = 0; i < 2; ++i) {
        int row = m0 + mw + i * 16 + lq * 4;
#pragma unroll
        for (int j = 0; j < 4; ++j) {
            int col = n0 + nw + j * 16 + lr;
            float bv = (EPI != 0) ? bias[col] : 0.f;
#pragma unroll
            for (int r = 0; r < 4; ++r) {
                float v = acc[i][j][r] + bv;
                size_t off = (size_t)(row + r) * N + col;
                if (EPI == 0) {
                    Cf[off] = v + resf[resStr * z + off];
                } else {
                    Cf[off] = v + b2f(resb[off]);
                }
            }
        }
    }
}

// ======================= bf16 MFMA GEMM: 128x128 tile ============================
// vmcnt(8) pipeline; T1 XCD swizzle. EPI=1: bias+gelu, bf16 out via LDS-staged
// coalesced stores.
template <int EPI>
__global__ __launch_bounds__(256) void gemm128(
    const u16* __restrict__ A, const u16* __restrict__ Bm,
    const float* __restrict__ bias, const void* __restrict__ res,
    void* __restrict__ Cout, int K, int N, int lda, int ldb,
    size_t aStr, size_t bStr, size_t cStr, size_t resStr)
{
    __shared__ __align__(16) u16 lds[32768];   // 64 KB
    int gx = gridDim.x, gy = gridDim.y;
    int wg = blockIdx.x + gx * (blockIdx.y + gy * blockIdx.z);
    int nwg = gx * gy * gridDim.z;
    wg = (wg & 7) * (nwg >> 3) + (wg >> 3);
    int z = wg / (gx * gy);
    int rem = wg - z * (gx * gy);
    int by = rem / gx, bx = rem - by * gx;
    int m0 = by * 128, n0 = bx * 128;
    int tid = threadIdx.x;
    int lane = tid & 63, wv = tid >> 6;

    const u16* ag[4]; const u16* bg[4];
    u32 la[4], lb[4];
#pragma unroll
    for (int i = 0; i < 4; ++i) {
        int q = i * 256 + tid;
        int row = q >> 3, c = q & 7;
        ag[i] = A + aStr * z + (size_t)(m0 + row) * lda + (c ^ (row & 7)) * 8;
        la[i] = i * 2048 + wv * 512;
        bg[i] = Bm + bStr * z + (size_t)(n0 + row) * ldb + (c ^ (row & 7)) * 8;
        lb[i] = 16384 + i * 2048 + wv * 512;
    }

    int mw = (wv >> 1) * 64, nw = (wv & 1) * 64;
    int lr = lane & 15, lq = lane >> 4;
    int sw = lr & 7;

    ffrag acc[4][4];
#pragma unroll
    for (int i = 0; i < 4; ++i)
#pragma unroll
        for (int j = 0; j < 4; ++j) acc[i][j] = (ffrag){0.f, 0.f, 0.f, 0.f};

#pragma unroll
    for (int i = 0; i < 4; ++i) gload_lds16(ag[i], &lds[la[i]]);
#pragma unroll
    for (int i = 0; i < 4; ++i) gload_lds16(bg[i], &lds[lb[i]]);

    for (int k0 = 0; k0 < K; k0 += 64) {
        int cur = (k0 >> 6) & 1;
        if (k0 + 64 < K) {
#pragma unroll
            for (int i = 0; i < 4; ++i)
                gload_lds16(ag[i] + k0 + 64, &lds[((cur ^ 1) << 13) + la[i]]);
#pragma unroll
            for (int i = 0; i < 4; ++i)
                gload_lds16(bg[i] + k0 + 64, &lds[((cur ^ 1) << 13) + lb[i]]);
            asm volatile("s_waitcnt vmcnt(8)" ::: "memory");
        } else {
            asm volatile("s_waitcnt vmcnt(0)" ::: "memory");
        }
        asm volatile("s_barrier" ::: "memory");

        const u16* Ab = &lds[cur << 13];
        const u16* Bb = &lds[16384 + (cur << 13)];
#pragma unroll
        for (int h = 0; h < 2; ++h) {
            bfrag af[4], bf[4];
#pragma unroll
            for (int i = 0; i < 4; ++i)
                af[i] = *(const bfrag*)&Ab[(mw + i * 16 + lr) * 64 + ((h * 4 + lq) ^ sw) * 8];
#pragma unroll
            for (int j = 0; j < 4; ++j)
                bf[j] = *(const bfrag*)&Bb[(nw + j * 16 + lr) * 64 + ((h * 4 + lq) ^ sw) * 8];
#pragma unroll
            for (int i = 0; i < 4; ++i)
#pragma unroll
                for (int j = 0; j < 4; ++j)
                    acc[i][j] = __builtin_amdgcn_mfma_f32_16x16x32_bf16(af[i], bf[j], acc[i][j], 0, 0, 0);
        }
        asm volatile("s_waitcnt lgkmcnt(0)\ns_barrier" ::: "memory");
    }

    float* Cf = (float*)Cout + cStr * z;
    u16*   Cb = (u16*)Cout + cStr * z;
    const float* resf = (const float*)res;
    const u16*   resb = (const u16*)res;
    if (EPI == 1) {
        u16* sb = lds;
#pragma unroll
        for (int i = 0; i < 4; ++i) {
            int rr = mw + i * 16 + lq * 4;
#pragma unroll
            for (int j = 0; j < 4; ++j) {
                int cc = nw + j * 16 + lr;
                float bv = bias[n0 + cc];
#pragma unroll
                for (int r = 0; r < 4; ++r)
                    sb[(rr + r) * 136 + cc] = f2b(gelu_cheap(acc[i][j][r] + bv));
            }
        }
        __syncthreads();
        u16* Crow = Cb + (size_t)m0 * N + n0;
#pragma unroll
        for (int t = 0; t < 8; ++t) {
            int q = t * 256 + tid;           // 2048 x 16B chunks
            int row = q >> 4, c16 = q & 15;
            *(uint4*)(Crow + (size_t)row * N + c16 * 8) =
                *(const uint4*)(sb + row * 136 + c16 * 8);
        }
    } else {
#pragma unroll
        for (int i = 0; i < 4; ++i) {
            int row = m0 + mw + i * 16 + lq * 4;
#pragma unroll
            for (int j = 0; j < 4; ++j) {
                int col = n0 + nw + j * 16 + lr;
                float bv = (EPI != 0) ? bias[col] : 0.f;
#pragma unroll
                for (int r = 0; r < 4; ++r) {
                    float v = acc[i][j][r] + bv;
                    size_t off = (size_t)(row + r) * N + col;
                    if (EPI == 0) {
                        Cf[off] = v + resf[resStr * z + off];
                    } else {
                        Cf[off] = v + b2f(resb[off]);
                    }
                }
            }
        }
    }
}

// ---------------- layernorm over D=512, one row per block ------------------------
// BF=true: write bf16, else fp32. SP=true: also emit si/sj for NEXT layer.
template <bool BF, bool SP>
__global__ __launch_bounds__(256) void ln_kernel(
    const float* __restrict__ in, const float* __restrict__ g,
    const float* __restrict__ be, void* __restrict__ out,
    const float* __restrict__ aw, float* __restrict__ si, float* __restrict__ sj)
{
    int row = blockIdx.x;
    int tid = threadIdx.x;
    const float2* rp = (const float2*)(in + (size_t)row * DD);
    float2 v = rp[tid];
    float s  = v.x + v.y;
    float ss = v.x * v.x + v.y * v.y;
#pragma unroll
    for (int off = 32; off > 0; off >>= 1) {
        s  += __shfl_xor(s, off);
        ss += __shfl_xor(ss, off);
    }
    __shared__ float sh[8];
    int wave = tid >> 6, lane = tid & 63;
    if (lane == 0) { sh[wave] = s; sh[4 + wave] = ss; }
    __syncthreads();
    float S  = sh[0] + sh[1] + sh[2] + sh[3];
    float SS = sh[4] + sh[5] + sh[6] + sh[7];
    float mean = S * (1.f / DD);
    float var  = SS * (1.f / DD) - mean * mean;
    var = fmaxf(var, 0.f);
    float rs = rsqrtf(var + 1e-5f);
    float2 gv = ((const float2*)g)[tid];
    float2 bv = ((const float2*)be)[tid];
    float ox = (v.x - mean) * rs * gv.x + bv.x;
    float oy = (v.y - mean) * rs * gv.y + bv.y;
    if (BF) {
        u32 w = (u32)f2b(ox) | ((u32)f2b(oy) << 16);
        ((u32*)out)[(size_t)row * (DD / 2) + tid] = w;
    } else {
        float2 o; o.x = ox; o.y = oy;
        ((float2*)out)[(size_t)row * (DD / 2) + tid] = o;
    }
    if (SP) {
        float2 wa = ((const float2*)aw)[tid];
        float2 wb = ((const float2*)(aw + DD))[tid];
        float a = ox * wa.x + oy * wa.y;
        float c = ox * wb.x + oy * wb.y;
#pragma unroll
        for (int off = 32; off > 0; off >>= 1) {
            a += __shfl_xor(a, off);
            c += __shfl_xor(c, off);
        }
        __syncthreads();                 // sh reuse
        if (lane == 0) { sh[wave] = a; sh[4 + wave] = c; }
        __syncthreads();
        if (tid == 0) {
            si[row] = sh[0] + sh[1] + sh[2] + sh[3];
            sj[row] = sh[4] + sh[5] + sh[6] + sh[7];
        }
    }
}

extern "C" void kernel_launch(void* const* d_in, const int* in_sizes, int n_in,
                              void* d_out, int out_size, void* d_ws, size_t ws_size,
                              hipStream_t stream) {
    const float* nf     = (const float*)d_in[0];
    const int*   adj    = (const int*)d_in[1];
    const float* attn_w = (const float*)d_in[2];
    const float* attn_b = (const float*)d_in[3];
    const float* W1     = (const float*)d_in[4];
    const float* b1     = (const float*)d_in[5];
    const float* W2     = (const float*)d_in[6];
    const float* b2     = (const float*)d_in[7];
    const float* g1     = (const float*)d_in[8];
    const float* be1    = (const float*)d_in[9];
    const float* g2     = (const float*)d_in[10];
    const float* be2    = (const float*)d_in[11];
    float* out = (float*)d_out;

    char* wsb = (char*)d_ws;
    float* x_cur = (float*)(wsb);                      // 16 MB [0,16M)
    u16*   h_bf  = (u16*)(wsb + 16777216);             //  8 MB [16,24M)
    char*  scr   = wsb + 25165824;                     // 32 MB [24,56M)
    float* hres  = (float*)(scr + 16777216);           //   [40,56M)
    u16*   mid   = (u16*)scr;                          //   [24,56M) after ln1 (hres dead)
    u16*   xT    = (u16*)(wsb + 58720256);             //  8 MB [56,64M)
    u16*   W1t   = (u16*)(wsb + 67108864);             //  6 MB [64,70M)
    u16*   W2t   = (u16*)(wsb + 73400320);             //  6 MB [70,76M)
    u64*   mask  = (u64*)(wsb + 79691776);             //  1 MB [76,77M)
    float* si    = (float*)(wsb + 80740352);           // 32 KB
    float* sj    = (float*)(wsb + 80773120);           // 32 KB

    // prep, 2 dispatches: {mask + layer-0 scores + nf->xT} and {both weight sets}
    prep_fused<<<6656, 256, 0, stream>>>(adj, mask, nf, attn_w, si, sj, xT);
    trans_w<<<dim3(64, 16, 6), 256, 0, stream>>>(W1, W2, W1t, W2t);

    for (int l = 0; l < 3; ++l) {
        const float* xin = (l == 0) ? nf : x_cur;
        if (l > 0) {
            transpose_cvt<<<dim3(16, 32, 8), 256, 0, stream>>>(xin, xT, 1024, 512,
                                                               (size_t)NN * DD, (size_t)NN * DD);
        }
        // fused softmax + agg: hres[b] = softmax(scores)[b] @ x[b]^T + x[b]
        agg_fused<<<dim3(4, 16, 8), 256, 0, stream>>>(
            si, sj, attn_b + l, mask, xT, xin, hres);
        // ln1 -> bf16 h
        ln_kernel<true, false><<<8192, 256, 0, stream>>>(
            hres, g1 + (size_t)l * 512, be1 + (size_t)l * 512, h_bf, nullptr, nullptr, nullptr);
        // FFN1: mid = gelu(h @ W1 + b1)  (bf16 out; 128x128 tiles, 1024 blocks, K=512)
        gemm128<1><<<dim3(16, 64, 1), 256, 0, stream>>>(
            h_bf, W1t + (size_t)l * 1048576, b1 + (size_t)l * 2048, nullptr, mid,
            512, 2048, 512, 512, 0, 0, 0, 0);
        // FFN2: x_cur = mid @ W2 + b2 + h   (512 blocks, K=2048)
        gemm64<2><<<dim3(4, 128, 1), 256, 0, stream>>>(
            mid, W2t + (size_t)l * 1048576, b2 + (size_t)l * 512, h_bf, x_cur,
            2048, 512, 2048, 2048, 0, 0, 0, 0);
        if (l < 2) {
            ln_kernel<false, true><<<8192, 256, 0, stream>>>(
                x_cur, g2 + (size_t)l * 512, be2 + (size_t)l * 512, x_cur,
                attn_w + (size_t)(l + 1) * 1024, si, sj);
        } else {
            ln_kernel<false, false><<<8192, 256, 0, stream>>>(
                x_cur, g2 + (size_t)l * 512, be2 + (size_t)l * 512, out,
                nullptr, nullptr, nullptr);
        }
    }
}

// Round 10
// 451.499 us; speedup vs baseline: 1.1652x; 1.1652x over previous
//
#include <hip/hip_runtime.h>
#include <math.h>

#define NB 8
#define NN 1024
#define DD 512

typedef unsigned short u16;
typedef unsigned int u32;
typedef unsigned long long u64;
typedef __attribute__((ext_vector_type(8))) short bfrag;
typedef __attribute__((ext_vector_type(4))) float ffrag;

__device__ __forceinline__ u16 f2b(float f) {
    union { float f; u32 u; } v; v.f = f;
    u32 r = v.u + 0x7fffu + ((v.u >> 16) & 1u);   // RNE
    return (u16)(r >> 16);
}
__device__ __forceinline__ float b2f(u16 b) {
    union { u32 u; float f; } v; v.u = ((u32)b) << 16;
    return v.f;
}

// A&S 7.1.26 erf: |err| <= 1.5e-7
__device__ __forceinline__ float gelu_cheap(float v) {
    float s = v * 0.70710678118654752f;
    float a = fabsf(s);
    float t = 1.0f / (1.0f + 0.3275911f * a);
    float p = ((((1.061405429f * t - 1.453152027f) * t + 1.421413741f) * t
                - 0.284496736f) * t + 0.254829592f) * t;
    float erfa = 1.0f - p * __expf(-a * a);
    float erfs = copysignf(erfa, s);
    return 0.5f * v * (1.0f + erfs);
}

// async global->LDS, 16B per lane; lds base must be wave-uniform
__device__ __forceinline__ void gload_lds16(const void* g, void* l) {
    __builtin_amdgcn_global_load_lds(
        (const __attribute__((address_space(1))) void*)g,
        (__attribute__((address_space(3))) void*)l, 16, 0, 0);
}

// ---------------- shared transpose body: fp32 [R][C] tile -> bf16 [C][R] ---------
__device__ __forceinline__ void tcvt_body(
    const float* __restrict__ in, u16* __restrict__ out,
    int R, int C, int r0, int c0, int t, float tile[32][33])
{
    int tr = t >> 3, tc = (t & 7) * 4;
    float4 v = *(const float4*)(in + (size_t)(r0 + tr) * C + c0 + tc);
    tile[tr][tc + 0] = v.x; tile[tr][tc + 1] = v.y;
    tile[tr][tc + 2] = v.z; tile[tr][tc + 3] = v.w;
    __syncthreads();
    u32 w0 = (u32)f2b(tile[tc + 0][tr]) | ((u32)f2b(tile[tc + 1][tr]) << 16);
    u32 w1 = (u32)f2b(tile[tc + 2][tr]) | ((u32)f2b(tile[tc + 3][tr]) << 16);
    uint2 wv; wv.x = w0; wv.y = w1;
    *(uint2*)(out + (size_t)(c0 + tr) * R + r0 + tc) = wv;
}

// ---------------- per-layer transpose + cvt: x fp32 [1024][512] -> xT bf16 -------
__global__ __launch_bounds__(256) void transpose_cvt(
    const float* __restrict__ in, u16* __restrict__ out,
    int R, int C, size_t inStr, size_t outStr)
{
    __shared__ float tile[32][33];
    int z = blockIdx.z;
    tcvt_body(in + inStr * z, out + outStr * z,
              R, C, blockIdx.y * 32, blockIdx.x * 32, threadIdx.x, tile);
}

// ---------------- fused prep: mask_pack + score_proj(l0) + transpose(nf->xT) -----
// flat grid 6656 blocks: [0,512) mask | [512,2560) score | [2560,6656) nf-transpose
__global__ __launch_bounds__(256) void prep_fused(
    const int* __restrict__ adj, u64* __restrict__ mb,
    const float* __restrict__ nf, const float* __restrict__ attn_w,
    float* __restrict__ si, float* __restrict__ sj, u16* __restrict__ xT)
{
    __shared__ float tile[32][33];
    int bid = blockIdx.x;
    int tid = threadIdx.x;
    if (bid < 512) {
        // ---- mask pack: adj + diag -> bitmask [B*N][16] u64 ----
        int idx = bid * 256 + tid;
        int w = idx & 15;
        int bi = idx >> 4;
        int i = bi & 1023;
        const int4* p = (const int4*)(adj + (size_t)bi * NN + w * 64);
        u64 m = 0;
#pragma unroll
        for (int q = 0; q < 16; ++q) {
            int4 v = p[q];
            if (v.x > 0) m |= 1ull << (q * 4 + 0);
            if (v.y > 0) m |= 1ull << (q * 4 + 1);
            if (v.z > 0) m |= 1ull << (q * 4 + 2);
            if (v.w > 0) m |= 1ull << (q * 4 + 3);
        }
        if (w == (i >> 6)) m |= 1ull << (i & 63);
        mb[idx] = m;
    } else if (bid < 2560) {
        // ---- score projection for layer 0 ----
        int wave = tid >> 6;
        int lane = tid & 63;
        int row = (bid - 512) * 4 + wave;
        const float4* xr = (const float4*)(nf + (size_t)row * DD) + lane * 2;
        const float4* w1 = (const float4*)(attn_w) + lane * 2;
        const float4* w2 = (const float4*)(attn_w + DD) + lane * 2;
        float a = 0.f, b2 = 0.f;
#pragma unroll
        for (int c = 0; c < 2; ++c) {
            float4 xv = xr[c], wa = w1[c], wb = w2[c];
            a  += xv.x * wa.x + xv.y * wa.y + xv.z * wa.z + xv.w * wa.w;
            b2 += xv.x * wb.x + xv.y * wb.y + xv.z * wb.z + xv.w * wb.w;
        }
#pragma unroll
        for (int off = 32; off > 0; off >>= 1) {
            a  += __shfl_xor(a, off);
            b2 += __shfl_xor(b2, off);
        }
        if (lane == 0) { si[row] = a; sj[row] = b2; }
    } else {
        // ---- transpose nf -> xT (layer 0): 8 batches of [1024][512] -> [512][1024]
        int q = bid - 2560;               // 0..4095
        int bx = q & 15, by = (q >> 4) & 31, bz = q >> 9;
        tcvt_body(nf + (size_t)bz * NN * DD, xT + (size_t)bz * NN * DD,
                  1024, 512, by * 32, bx * 32, tid, tile);
    }
}

// ---------------- weight transposes, both in one dispatch ------------------------
// grid (64,16,6): z<3 -> W1 layer z [512][2048]->[2048][512]; z>=3 -> W2 layer z-3
__global__ __launch_bounds__(256) void trans_w(
    const float* __restrict__ W1, const float* __restrict__ W2,
    u16* __restrict__ W1t, u16* __restrict__ W2t)
{
    __shared__ float tile[32][33];
    int z = blockIdx.z;
    int bx = blockIdx.x, by = blockIdx.y;
    if (z < 3) {
        tcvt_body(W1 + (size_t)z * 512 * 2048, W1t + (size_t)z * 1048576,
                  512, 2048, by * 32, bx * 32, threadIdx.x, tile);
    } else {
        int q = by * 64 + bx;             // 0..1023
        int bx2 = q & 15, by2 = q >> 4;   // (16, 64)
        tcvt_body(W2 + (size_t)(z - 3) * 2048 * 512, W2t + (size_t)(z - 3) * 1048576,
                  2048, 512, by2 * 32, bx2 * 32, threadIdx.x, tile);
    }
}

// ---------------- softmax -> P (bf16), register-resident -------------------------
__global__ __launch_bounds__(256) void softmax_p(
    const float* __restrict__ si, const float* __restrict__ sj,
    const float* __restrict__ attn_b, const u64* __restrict__ mb,
    u16* __restrict__ P)
{
    __shared__ u16 sb[8 * NN];        // 16 KB
    int b  = blockIdx.x >> 7;
    int i0 = (blockIdx.x & 127) * 8;
    int tid = threadIdx.x;
    int r = tid >> 5, l32 = tid & 31;
    int i = i0 + r;
    float bb = attn_b[0];
    float siv = si[b * NN + i];
    const float* sjb = sj + b * NN;
    const u64* mbr = mb + ((size_t)b * NN + i) * 16;

    float sv[32];
    float mx = -INFINITY;
#pragma unroll
    for (int q = 0; q < 32; ++q) {
        int j = q * 32 + l32;
        u64 w = mbr[q >> 1];
        int bit = ((q & 1) << 5) + l32;
        float s = siv + sjb[j] + bb;
        s = (s >= 0.f) ? s : 0.2f * s;
        s = ((w >> bit) & 1ull) ? s : -INFINITY;
        sv[q] = s;
        mx = fmaxf(mx, s);
    }
#pragma unroll
    for (int off = 16; off > 0; off >>= 1) mx = fmaxf(mx, __shfl_xor(mx, off, 32));
    float sum = 0.f;
#pragma unroll
    for (int q = 0; q < 32; ++q) {
        float p = __expf(sv[q] - mx);
        sv[q] = p;
        sum += p;
    }
#pragma unroll
    for (int off = 16; off > 0; off >>= 1) sum += __shfl_xor(sum, off, 32);
    float inv = 1.f / sum;
#pragma unroll
    for (int q = 0; q < 32; ++q)
        sb[r * NN + q * 32 + l32] = f2b(sv[q] * inv);
    __syncthreads();
    const uint4* src = (const uint4*)sb;
    uint4* dst = (uint4*)(P + ((size_t)b * NN + i0) * NN);
#pragma unroll
    for (int t = 0; t < 4; ++t) dst[t * 256 + tid] = src[t * 256 + tid];
}

// ======================= bf16 MFMA GEMM: 64x128 tile, BK=64, LDS double-buffer ===
// AITER-style pipeline: prefetch next tile's global_load_lds, then
// s_waitcnt vmcnt(6) (waits only current tile) + raw s_barrier — prefetch stays
// in flight across the barrier. XOR swizzle (col^row&7) folded into global addr.
// T1: XCD-chunked blockIdx swizzle (all call-site grids are multiples of 8).
// EPI: 0 = +res(fp32), fp32 out | 2 = +bias +res(bf16), fp32 out
template <int EPI>
__global__ __launch_bounds__(256) void gemm64(
    const u16* __restrict__ A, const u16* __restrict__ Bm,
    const float* __restrict__ bias, const void* __restrict__ res,
    void* __restrict__ Cout, int K, int N, int lda, int ldb,
    size_t aStr, size_t bStr, size_t cStr, size_t resStr)
{
    // layout (u16 elems): A buf0 [0,4096) buf1 [4096,8192); B buf0 [8192,16384) buf1 [16384,24576)
    __shared__ __align__(16) u16 lds[24576];   // 48 KB
    // ---- T1 XCD swizzle: physical id p -> logical chunk (p%8)*cpx + p/8 ----
    int gx = gridDim.x, gy = gridDim.y;
    int wg = blockIdx.x + gx * (blockIdx.y + gy * blockIdx.z);
    int nwg = gx * gy * gridDim.z;
    wg = (wg & 7) * (nwg >> 3) + (wg >> 3);
    int z = wg / (gx * gy);
    int rem = wg - z * (gx * gy);
    int by = rem / gx, bx = rem - by * gx;
    int m0 = by * 64, n0 = bx * 128;
    int tid = threadIdx.x;
    int lane = tid & 63, wv = tid >> 6;

    const u16* ag[2]; const u16* bg[4];
    u32 la[2], lb[4];
#pragma unroll
    for (int i = 0; i < 2; ++i) {
        int q = i * 256 + tid;
        int row = q >> 3, c = q & 7;
        ag[i] = A + aStr * z + (size_t)(m0 + row) * lda + (c ^ (row & 7)) * 8;
        la[i] = i * 2048 + wv * 512;
    }
#pragma unroll
    for (int i = 0; i < 4; ++i) {
        int q = i * 256 + tid;
        int row = q >> 3, c = q & 7;
        bg[i] = Bm + bStr * z + (size_t)(n0 + row) * ldb + (c ^ (row & 7)) * 8;
        lb[i] = 8192 + i * 2048 + wv * 512;
    }

    int mw = (wv >> 1) * 32, nw = (wv & 1) * 64;
    int lr = lane & 15, lq = lane >> 4;
    int sw = lr & 7;

    ffrag acc[2][4];
#pragma unroll
    for (int i = 0; i < 2; ++i)
#pragma unroll
        for (int j = 0; j < 4; ++j) acc[i][j] = (ffrag){0.f, 0.f, 0.f, 0.f};

    // prologue: stage k=0 into buf0
#pragma unroll
    for (int i = 0; i < 2; ++i) gload_lds16(ag[i], &lds[la[i]]);
#pragma unroll
    for (int i = 0; i < 4; ++i) gload_lds16(bg[i], &lds[lb[i]]);

    for (int k0 = 0; k0 < K; k0 += 64) {
        int cur = (k0 >> 6) & 1;
        if (k0 + 64 < K) {
            // prefetch next tile into other buffer (6 loads stay in flight)
#pragma unroll
            for (int i = 0; i < 2; ++i)
                gload_lds16(ag[i] + k0 + 64, &lds[((cur ^ 1) << 12) + la[i]]);
#pragma unroll
            for (int i = 0; i < 4; ++i)
                gload_lds16(bg[i] + k0 + 64, &lds[((cur ^ 1) << 13) + lb[i]]);
            asm volatile("s_waitcnt vmcnt(6)" ::: "memory");
        } else {
            asm volatile("s_waitcnt vmcnt(0)" ::: "memory");
        }
        asm volatile("s_barrier" ::: "memory");   // all waves: cur tile resident

        const u16* Ab = &lds[cur << 12];
        const u16* Bb = &lds[8192 + (cur << 13)];
#pragma unroll
        for (int h = 0; h < 2; ++h) {
            bfrag af[2], bf[4];
#pragma unroll
            for (int i = 0; i < 2; ++i)
                af[i] = *(const bfrag*)&Ab[(mw + i * 16 + lr) * 64 + ((h * 4 + lq) ^ sw) * 8];
#pragma unroll
            for (int j = 0; j < 4; ++j)
                bf[j] = *(const bfrag*)&Bb[(nw + j * 16 + lr) * 64 + ((h * 4 + lq) ^ sw) * 8];
#pragma unroll
            for (int i = 0; i < 2; ++i)
#pragma unroll
                for (int j = 0; j < 4; ++j)
                    acc[i][j] = __builtin_amdgcn_mfma_f32_16x16x32_bf16(af[i], bf[j], acc[i][j], 0, 0, 0);
        }
        // all waves done reading cur before next iter overwrites it
        asm volatile("s_waitcnt lgkmcnt(0)\ns_barrier" ::: "memory");
    }

    float* Cf = (float*)Cout + cStr * z;
    const float* resf = (const float*)res;
    const u16*   resb = (const u16*)res;
#pragma unroll
    for (int i = 0; i < 2; ++i) {
        int row = m0 + mw + i * 16 + lq * 4;
#pragma unroll
        for (int j = 0; j < 4; ++j) {
            int col = n0 + nw + j * 16 + lr;
            float bv = (EPI != 0) ? bias[col] : 0.f;
#pragma unroll
            for (int r = 0; r < 4; ++r) {
                float v = acc[i][j][r] + bv;
                size_t off = (size_t)(row + r) * N + col;
                if (EPI == 0) {
                    Cf[off] = v + resf[resStr * z + off];
                } else {
                    Cf[off] = v + b2f(resb[off]);
                }
            }
        }
    }
}

// ======================= bf16 MFMA GEMM: 128x128 tile ============================
// Same AITER-style vmcnt pipeline, 8 staging loads/tile -> vmcnt(8).
// T1 XCD swizzle. EPI=1 epilogue routes the C-tile through LDS so the bf16 output
// is written as 16B/lane coalesced streams instead of 32B scattered segments.
template <int EPI>
__global__ __launch_bounds__(256) void gemm128(
    const u16* __restrict__ A, const u16* __restrict__ Bm,
    const float* __restrict__ bias, const void* __restrict__ res,
    void* __restrict__ Cout, int K, int N, int lda, int ldb,
    size_t aStr, size_t bStr, size_t cStr, size_t resStr)
{
    // layout (u16 elems): A buf0 [0,8192) buf1 [8192,16384); B buf0 [16384,24576) buf1 [24576,32768)
    __shared__ __align__(16) u16 lds[32768];   // 64 KB
    // ---- T1 XCD swizzle ----
    int gx = gridDim.x, gy = gridDim.y;
    int wg = blockIdx.x + gx * (blockIdx.y + gy * blockIdx.z);
    int nwg = gx * gy * gridDim.z;
    wg = (wg & 7) * (nwg >> 3) + (wg >> 3);
    int z = wg / (gx * gy);
    int rem = wg - z * (gx * gy);
    int by = rem / gx, bx = rem - by * gx;
    int m0 = by * 128, n0 = bx * 128;
    int tid = threadIdx.x;
    int lane = tid & 63, wv = tid >> 6;

    const u16* ag[4]; const u16* bg[4];
    u32 la[4], lb[4];
#pragma unroll
    for (int i = 0; i < 4; ++i) {
        int q = i * 256 + tid;
        int row = q >> 3, c = q & 7;       // row in [0,128)
        ag[i] = A + aStr * z + (size_t)(m0 + row) * lda + (c ^ (row & 7)) * 8;
        la[i] = i * 2048 + wv * 512;
        bg[i] = Bm + bStr * z + (size_t)(n0 + row) * ldb + (c ^ (row & 7)) * 8;
        lb[i] = 16384 + i * 2048 + wv * 512;
    }

    int mw = (wv >> 1) * 64, nw = (wv & 1) * 64;
    int lr = lane & 15, lq = lane >> 4;
    int sw = lr & 7;

    ffrag acc[4][4];
#pragma unroll
    for (int i = 0; i < 4; ++i)
#pragma unroll
        for (int j = 0; j < 4; ++j) acc[i][j] = (ffrag){0.f, 0.f, 0.f, 0.f};

    // prologue: stage k=0 into buf0
#pragma unroll
    for (int i = 0; i < 4; ++i) gload_lds16(ag[i], &lds[la[i]]);
#pragma unroll
    for (int i = 0; i < 4; ++i) gload_lds16(bg[i], &lds[lb[i]]);

    for (int k0 = 0; k0 < K; k0 += 64) {
        int cur = (k0 >> 6) & 1;
        if (k0 + 64 < K) {
            // prefetch next tile into other buffer (8 loads stay in flight)
#pragma unroll
            for (int i = 0; i < 4; ++i)
                gload_lds16(ag[i] + k0 + 64, &lds[((cur ^ 1) << 13) + la[i]]);
#pragma unroll
            for (int i = 0; i < 4; ++i)
                gload_lds16(bg[i] + k0 + 64, &lds[((cur ^ 1) << 13) + lb[i]]);
            asm volatile("s_waitcnt vmcnt(8)" ::: "memory");
        } else {
            asm volatile("s_waitcnt vmcnt(0)" ::: "memory");
        }
        asm volatile("s_barrier" ::: "memory");   // all waves: cur tile resident

        const u16* Ab = &lds[cur << 13];
        const u16* Bb = &lds[16384 + (cur << 13)];
#pragma unroll
        for (int h = 0; h < 2; ++h) {
            bfrag af[4], bf[4];
#pragma unroll
            for (int i = 0; i < 4; ++i)
                af[i] = *(const bfrag*)&Ab[(mw + i * 16 + lr) * 64 + ((h * 4 + lq) ^ sw) * 8];
#pragma unroll
            for (int j = 0; j < 4; ++j)
                bf[j] = *(const bfrag*)&Bb[(nw + j * 16 + lr) * 64 + ((h * 4 + lq) ^ sw) * 8];
#pragma unroll
            for (int i = 0; i < 4; ++i)
#pragma unroll
                for (int j = 0; j < 4; ++j)
                    acc[i][j] = __builtin_amdgcn_mfma_f32_16x16x32_bf16(af[i], bf[j], acc[i][j], 0, 0, 0);
        }
        // all waves done reading cur before next iter overwrites it
        asm volatile("s_waitcnt lgkmcnt(0)\ns_barrier" ::: "memory");
    }

    float* Cf = (float*)Cout + cStr * z;
    u16*   Cb = (u16*)Cout + cStr * z;
    const float* resf = (const float*)res;
    const u16*   resb = (const u16*)res;
    if (EPI == 1) {
        // stage bf16 C-tile in LDS (row stride 136 u16 = 272B, 16B-aligned,
        // lq-groups land on disjoint bank sets), then stream out coalesced.
        u16* sb = lds;
#pragma unroll
        for (int i = 0; i < 4; ++i) {
            int rr = mw + i * 16 + lq * 4;
#pragma unroll
            for (int j = 0; j < 4; ++j) {
                int cc = nw + j * 16 + lr;
                float bv = bias[n0 + cc];
#pragma unroll
                for (int r = 0; r < 4; ++r)
                    sb[(rr + r) * 136 + cc] = f2b(gelu_cheap(acc[i][j][r] + bv));
            }
        }
        __syncthreads();
        u16* Crow = Cb + (size_t)m0 * N + n0;
#pragma unroll
        for (int t = 0; t < 8; ++t) {
            int q = t * 256 + tid;           // 2048 x 16B chunks
            int row = q >> 4, c16 = q & 15;
            *(uint4*)(Crow + (size_t)row * N + c16 * 8) =
                *(const uint4*)(sb + row * 136 + c16 * 8);
        }
    } else {
#pragma unroll
        for (int i = 0; i < 4; ++i) {
            int row = m0 + mw + i * 16 + lq * 4;
#pragma unroll
            for (int j = 0; j < 4; ++j) {
                int col = n0 + nw + j * 16 + lr;
                float bv = (EPI != 0) ? bias[col] : 0.f;
#pragma unroll
                for (int r = 0; r < 4; ++r) {
                    float v = acc[i][j][r] + bv;
                    size_t off = (size_t)(row + r) * N + col;
                    if (EPI == 0) {
                        Cf[off] = v + resf[resStr * z + off];
                    } else {
                        Cf[off] = v + b2f(resb[off]);
                    }
                }
            }
        }
    }
}

// ---------------- layernorm over D=512, one row per block ------------------------
// BF=true: write bf16, else fp32. SP=true: also emit si/sj = x.w1, x.w2 for NEXT
// layer's attention scores (x-row is already in registers -> saves a 16MB re-read).
template <bool BF, bool SP>
__global__ __launch_bounds__(256) void ln_kernel(
    const float* __restrict__ in, const float* __restrict__ g,
    const float* __restrict__ be, void* __restrict__ out,
    const float* __restrict__ aw, float* __restrict__ si, float* __restrict__ sj)
{
    int row = blockIdx.x;
    int tid = threadIdx.x;
    const float2* rp = (const float2*)(in + (size_t)row * DD);
    float2 v = rp[tid];
    float s  = v.x + v.y;
    float ss = v.x * v.x + v.y * v.y;
#pragma unroll
    for (int off = 32; off > 0; off >>= 1) {
        s  += __shfl_xor(s, off);
        ss += __shfl_xor(ss, off);
    }
    __shared__ float sh[8];
    int wave = tid >> 6, lane = tid & 63;
    if (lane == 0) { sh[wave] = s; sh[4 + wave] = ss; }
    __syncthreads();
    float S  = sh[0] + sh[1] + sh[2] + sh[3];
    float SS = sh[4] + sh[5] + sh[6] + sh[7];
    float mean = S * (1.f / DD);
    float var  = SS * (1.f / DD) - mean * mean;
    var = fmaxf(var, 0.f);
    float rs = rsqrtf(var + 1e-5f);
    float2 gv = ((const float2*)g)[tid];
    float2 bv = ((const float2*)be)[tid];
    float ox = (v.x - mean) * rs * gv.x + bv.x;
    float oy = (v.y - mean) * rs * gv.y + bv.y;
    if (BF) {
        u32 w = (u32)f2b(ox) | ((u32)f2b(oy) << 16);
        ((u32*)out)[(size_t)row * (DD / 2) + tid] = w;
    } else {
        float2 o; o.x = ox; o.y = oy;
        ((float2*)out)[(size_t)row * (DD / 2) + tid] = o;
    }
    if (SP) {
        float2 wa = ((const float2*)aw)[tid];
        float2 wb = ((const float2*)(aw + DD))[tid];
        float a = ox * wa.x + oy * wa.y;
        float c = ox * wb.x + oy * wb.y;
#pragma unroll
        for (int off = 32; off > 0; off >>= 1) {
            a += __shfl_xor(a, off);
            c += __shfl_xor(c, off);
        }
        __syncthreads();                 // sh reuse
        if (lane == 0) { sh[wave] = a; sh[4 + wave] = c; }
        __syncthreads();
        if (tid == 0) {
            si[row] = sh[0] + sh[1] + sh[2] + sh[3];
            sj[row] = sh[4] + sh[5] + sh[6] + sh[7];
        }
    }
}

extern "C" void kernel_launch(void* const* d_in, const int* in_sizes, int n_in,
                              void* d_out, int out_size, void* d_ws, size_t ws_size,
                              hipStream_t stream) {
    const float* nf     = (const float*)d_in[0];
    const int*   adj    = (const int*)d_in[1];
    const float* attn_w = (const float*)d_in[2];
    const float* attn_b = (const float*)d_in[3];
    const float* W1     = (const float*)d_in[4];
    const float* b1     = (const float*)d_in[5];
    const float* W2     = (const float*)d_in[6];
    const float* b2     = (const float*)d_in[7];
    const float* g1     = (const float*)d_in[8];
    const float* be1    = (const float*)d_in[9];
    const float* g2     = (const float*)d_in[10];
    const float* be2    = (const float*)d_in[11];
    float* out = (float*)d_out;

    char* wsb = (char*)d_ws;
    float* x_cur = (float*)(wsb);                      // 16 MB [0,16M)
    u16*   h_bf  = (u16*)(wsb + 16777216);             //  8 MB [16,24M)
    char*  scr   = wsb + 25165824;                     // 32 MB [24,56M)
    u16*   P     = (u16*)scr;                          //   [24,40M)
    float* hres  = (float*)(scr + 16777216);           //   [40,56M)
    u16*   mid   = (u16*)scr;                          //   [24,56M) after ln1 (P,hres dead)
    u16*   xT    = (u16*)(wsb + 58720256);             //  8 MB [56,64M)
    u16*   W1t   = (u16*)(wsb + 67108864);             //  6 MB [64,70M)
    u16*   W2t   = (u16*)(wsb + 73400320);             //  6 MB [70,76M)
    u64*   mask  = (u64*)(wsb + 79691776);             //  1 MB [76,77M)
    float* si    = (float*)(wsb + 80740352);           // 32 KB
    float* sj    = (float*)(wsb + 80773120);           // 32 KB

    // prep, 2 dispatches: {mask + layer-0 scores + nf->xT} and {both weight sets}
    prep_fused<<<6656, 256, 0, stream>>>(adj, mask, nf, attn_w, si, sj, xT);
    trans_w<<<dim3(64, 16, 6), 256, 0, stream>>>(W1, W2, W1t, W2t);

    for (int l = 0; l < 3; ++l) {
        const float* xin = (l == 0) ? nf : x_cur;
        if (l > 0) {
            transpose_cvt<<<dim3(16, 32, 8), 256, 0, stream>>>(xin, xT, 1024, 512,
                                                               (size_t)NN * DD, (size_t)NN * DD);
        }
        softmax_p<<<1024, 256, 0, stream>>>(si, sj, attn_b + l, mask, P);
        // agg: hres[b] = P[b] @ x[b]^T + x[b]   (64x128 tiles, 512 blocks, K=1024)
        gemm64<0><<<dim3(4, 16, 8), 256, 0, stream>>>(
            P, xT, nullptr, xin, hres, 1024, 512, 1024, 1024,
            (size_t)NN * NN, (size_t)DD * NN, (size_t)NN * DD, (size_t)NN * DD);
        // ln1 -> bf16 h
        ln_kernel<true, false><<<8192, 256, 0, stream>>>(
            hres, g1 + (size_t)l * 512, be1 + (size_t)l * 512, h_bf, nullptr, nullptr, nullptr);
        // FFN1: mid = gelu(h @ W1 + b1)  (bf16 out; 128x128 tiles, 1024 blocks, K=512)
        gemm128<1><<<dim3(16, 64, 1), 256, 0, stream>>>(
            h_bf, W1t + (size_t)l * 1048576, b1 + (size_t)l * 2048, nullptr, mid,
            512, 2048, 512, 512, 0, 0, 0, 0);
        // FFN2: x_cur = mid @ W2 + b2 + h   (512 blocks, K=2048)
        gemm64<2><<<dim3(4, 128, 1), 256, 0, stream>>>(
            mid, W2t + (size_t)l * 1048576, b2 + (size_t)l * 512, h_bf, x_cur,
            2048, 512, 2048, 2048, 0, 0, 0, 0);
        if (l < 2) {
            ln_kernel<false, true><<<8192, 256, 0, stream>>>(
                x_cur, g2 + (size_t)l * 512, be2 + (size_t)l * 512, x_cur,
                attn_w + (size_t)(l + 1) * 1024, si, sj);
        } else {
            ln_kernel<false, false><<<8192, 256, 0, stream>>>(
                x_cur, g2 + (size_t)l * 512, be2 + (size_t)l * 512, out,
                nullptr, nullptr, nullptr);
        }
    }
}

// Round 11
// 444.475 us; speedup vs baseline: 1.1836x; 1.0158x over previous
//
#include <hip/hip_runtime.h>
#include <math.h>

#define NB 8
#define NN 1024
#define DD 512

typedef unsigned short u16;
typedef unsigned int u32;
typedef unsigned long long u64;
typedef __attribute__((ext_vector_type(8))) short bfrag;
typedef __attribute__((ext_vector_type(4))) float ffrag;

__device__ __forceinline__ u16 f2b(float f) {
    union { float f; u32 u; } v; v.f = f;
    u32 r = v.u + 0x7fffu + ((v.u >> 16) & 1u);   // RNE
    return (u16)(r >> 16);
}
__device__ __forceinline__ float b2f(u16 b) {
    union { u32 u; float f; } v; v.u = ((u32)b) << 16;
    return v.f;
}

// A&S 7.1.26 erf: |err| <= 1.5e-7
__device__ __forceinline__ float gelu_cheap(float v) {
    float s = v * 0.70710678118654752f;
    float a = fabsf(s);
    float t = 1.0f / (1.0f + 0.3275911f * a);
    float p = ((((1.061405429f * t - 1.453152027f) * t + 1.421413741f) * t
                - 0.284496736f) * t + 0.254829592f) * t;
    float erfa = 1.0f - p * __expf(-a * a);
    float erfs = copysignf(erfa, s);
    return 0.5f * v * (1.0f + erfs);
}

// async global->LDS, 16B per lane; lds base must be wave-uniform
__device__ __forceinline__ void gload_lds16(const void* g, void* l) {
    __builtin_amdgcn_global_load_lds(
        (const __attribute__((address_space(1))) void*)g,
        (__attribute__((address_space(3))) void*)l, 16, 0, 0);
}

// ---------------- shared transpose body: fp32 [R][C] tile -> bf16 [C][R] ---------
__device__ __forceinline__ void tcvt_body(
    const float* __restrict__ in, u16* __restrict__ out,
    int R, int C, int r0, int c0, int t, float tile[32][33])
{
    int tr = t >> 3, tc = (t & 7) * 4;
    float4 v = *(const float4*)(in + (size_t)(r0 + tr) * C + c0 + tc);
    tile[tr][tc + 0] = v.x; tile[tr][tc + 1] = v.y;
    tile[tr][tc + 2] = v.z; tile[tr][tc + 3] = v.w;
    __syncthreads();
    u32 w0 = (u32)f2b(tile[tc + 0][tr]) | ((u32)f2b(tile[tc + 1][tr]) << 16);
    u32 w1 = (u32)f2b(tile[tc + 2][tr]) | ((u32)f2b(tile[tc + 3][tr]) << 16);
    uint2 wv; wv.x = w0; wv.y = w1;
    *(uint2*)(out + (size_t)(c0 + tr) * R + r0 + tc) = wv;
}

// ---------------- softmax body (verified softmax_p), sb = 16KB LDS ---------------
__device__ __forceinline__ void softmax_body(
    const float* __restrict__ si, const float* __restrict__ sj,
    const float* __restrict__ attn_b, const u64* __restrict__ mb,
    u16* __restrict__ P, int bid, int tid, u16* sb)
{
    int b  = bid >> 7;
    int i0 = (bid & 127) * 8;
    int r = tid >> 5, l32 = tid & 31;
    int i = i0 + r;
    float bb = attn_b[0];
    float siv = si[b * NN + i];
    const float* sjb = sj + b * NN;
    const u64* mbr = mb + ((size_t)b * NN + i) * 16;

    float sv[32];
    float mx = -INFINITY;
#pragma unroll
    for (int q = 0; q < 32; ++q) {
        int j = q * 32 + l32;
        u64 w = mbr[q >> 1];
        int bit = ((q & 1) << 5) + l32;
        float s = siv + sjb[j] + bb;
        s = (s >= 0.f) ? s : 0.2f * s;
        s = ((w >> bit) & 1ull) ? s : -INFINITY;
        sv[q] = s;
        mx = fmaxf(mx, s);
    }
#pragma unroll
    for (int off = 16; off > 0; off >>= 1) mx = fmaxf(mx, __shfl_xor(mx, off, 32));
    float sum = 0.f;
#pragma unroll
    for (int q = 0; q < 32; ++q) {
        float p = __expf(sv[q] - mx);
        sv[q] = p;
        sum += p;
    }
#pragma unroll
    for (int off = 16; off > 0; off >>= 1) sum += __shfl_xor(sum, off, 32);
    float inv = 1.f / sum;
#pragma unroll
    for (int q = 0; q < 32; ++q)
        sb[r * NN + q * 32 + l32] = f2b(sv[q] * inv);
    __syncthreads();
    const uint4* src = (const uint4*)sb;
    uint4* dst = (uint4*)(P + ((size_t)b * NN + i0) * NN);
#pragma unroll
    for (int t = 0; t < 4; ++t) dst[t * 256 + tid] = src[t * 256 + tid];
}

// ---------------- softmax -> P (bf16) standalone (layer 0) -----------------------
__global__ __launch_bounds__(256) void softmax_p(
    const float* __restrict__ si, const float* __restrict__ sj,
    const float* __restrict__ attn_b, const u64* __restrict__ mb,
    u16* __restrict__ P)
{
    __shared__ __align__(16) u16 sb[8 * NN];        // 16 KB
    softmax_body(si, sj, attn_b, mb, P, blockIdx.x, threadIdx.x, sb);
}

// -------- fused softmax + x-transpose for layers 1,2 (independent producers) -----
// flat grid 5120: [0,1024) softmax blocks | [1024,5120) transpose blocks.
// Both consume only previous-layer outputs (si/sj/x_cur) -> safe co-dispatch.
// Saves 2 dispatch boundaries/layer and overlaps the BW-bound transpose with the
// VALU-heavy softmax. LDS: 16 KB union (same cap as softmax_p -> no occupancy hit).
__global__ __launch_bounds__(256) void sm_xt_fused(
    const float* __restrict__ si, const float* __restrict__ sj,
    const float* __restrict__ attn_b, const u64* __restrict__ mb,
    u16* __restrict__ P, const float* __restrict__ xin, u16* __restrict__ xT)
{
    __shared__ __align__(16) u16 shmem[8 * NN];     // 16 KB (softmax) / 4.2 KB (tile)
    int bid = blockIdx.x;
    int tid = threadIdx.x;
    if (bid < 1024) {
        softmax_body(si, sj, attn_b, mb, P, bid, tid, shmem);
    } else {
        float (*tile)[33] = (float (*)[33])shmem;
        int q = bid - 1024;               // 0..4095
        int bx = q & 15, by = (q >> 4) & 31, bz = q >> 9;
        tcvt_body(xin + (size_t)bz * NN * DD, xT + (size_t)bz * NN * DD,
                  1024, 512, by * 32, bx * 32, tid, tile);
    }
}

// ---------------- fused prep: mask_pack + score_proj(l0) + transpose(nf->xT) -----
// flat grid 6656 blocks: [0,512) mask | [512,2560) score | [2560,6656) nf-transpose
__global__ __launch_bounds__(256) void prep_fused(
    const int* __restrict__ adj, u64* __restrict__ mb,
    const float* __restrict__ nf, const float* __restrict__ attn_w,
    float* __restrict__ si, float* __restrict__ sj, u16* __restrict__ xT)
{
    __shared__ float tile[32][33];
    int bid = blockIdx.x;
    int tid = threadIdx.x;
    if (bid < 512) {
        // ---- mask pack: adj + diag -> bitmask [B*N][16] u64 ----
        int idx = bid * 256 + tid;
        int w = idx & 15;
        int bi = idx >> 4;
        int i = bi & 1023;
        const int4* p = (const int4*)(adj + (size_t)bi * NN + w * 64);
        u64 m = 0;
#pragma unroll
        for (int q = 0; q < 16; ++q) {
            int4 v = p[q];
            if (v.x > 0) m |= 1ull << (q * 4 + 0);
            if (v.y > 0) m |= 1ull << (q * 4 + 1);
            if (v.z > 0) m |= 1ull << (q * 4 + 2);
            if (v.w > 0) m |= 1ull << (q * 4 + 3);
        }
        if (w == (i >> 6)) m |= 1ull << (i & 63);
        mb[idx] = m;
    } else if (bid < 2560) {
        // ---- score projection for layer 0 ----
        int wave = tid >> 6;
        int lane = tid & 63;
        int row = (bid - 512) * 4 + wave;
        const float4* xr = (const float4*)(nf + (size_t)row * DD) + lane * 2;
        const float4* w1 = (const float4*)(attn_w) + lane * 2;
        const float4* w2 = (const float4*)(attn_w + DD) + lane * 2;
        float a = 0.f, b2 = 0.f;
#pragma unroll
        for (int c = 0; c < 2; ++c) {
            float4 xv = xr[c], wa = w1[c], wb = w2[c];
            a  += xv.x * wa.x + xv.y * wa.y + xv.z * wa.z + xv.w * wa.w;
            b2 += xv.x * wb.x + xv.y * wb.y + xv.z * wb.z + xv.w * wb.w;
        }
#pragma unroll
        for (int off = 32; off > 0; off >>= 1) {
            a  += __shfl_xor(a, off);
            b2 += __shfl_xor(b2, off);
        }
        if (lane == 0) { si[row] = a; sj[row] = b2; }
    } else {
        // ---- transpose nf -> xT (layer 0): 8 batches of [1024][512] -> [512][1024]
        int q = bid - 2560;               // 0..4095
        int bx = q & 15, by = (q >> 4) & 31, bz = q >> 9;
        tcvt_body(nf + (size_t)bz * NN * DD, xT + (size_t)bz * NN * DD,
                  1024, 512, by * 32, bx * 32, tid, tile);
    }
}

// ---------------- weight transposes, both in one dispatch ------------------------
// grid (64,16,6): z<3 -> W1 layer z [512][2048]->[2048][512]; z>=3 -> W2 layer z-3
__global__ __launch_bounds__(256) void trans_w(
    const float* __restrict__ W1, const float* __restrict__ W2,
    u16* __restrict__ W1t, u16* __restrict__ W2t)
{
    __shared__ float tile[32][33];
    int z = blockIdx.z;
    int bx = blockIdx.x, by = blockIdx.y;
    if (z < 3) {
        tcvt_body(W1 + (size_t)z * 512 * 2048, W1t + (size_t)z * 1048576,
                  512, 2048, by * 32, bx * 32, threadIdx.x, tile);
    } else {
        int q = by * 64 + bx;             // 0..1023
        int bx2 = q & 15, by2 = q >> 4;   // (16, 64)
        tcvt_body(W2 + (size_t)(z - 3) * 2048 * 512, W2t + (size_t)(z - 3) * 1048576,
                  2048, 512, by2 * 32, bx2 * 32, threadIdx.x, tile);
    }
}

// ======================= bf16 MFMA GEMM: 64x128 tile, BK=64, LDS double-buffer ===
// AITER-style pipeline: prefetch next tile's global_load_lds, then
// s_waitcnt vmcnt(6) (waits only current tile) + raw s_barrier — prefetch stays
// in flight across the barrier. XOR swizzle (col^row&7) folded into global addr.
// T1: XCD-chunked blockIdx swizzle (all call-site grids are multiples of 8).
// EPI: 0 = +res(fp32), fp32 out | 2 = +bias +res(bf16), fp32 out
template <int EPI>
__global__ __launch_bounds__(256) void gemm64(
    const u16* __restrict__ A, const u16* __restrict__ Bm,
    const float* __restrict__ bias, const void* __restrict__ res,
    void* __restrict__ Cout, int K, int N, int lda, int ldb,
    size_t aStr, size_t bStr, size_t cStr, size_t resStr)
{
    // layout (u16 elems): A buf0 [0,4096) buf1 [4096,8192); B buf0 [8192,16384) buf1 [16384,24576)
    __shared__ __align__(16) u16 lds[24576];   // 48 KB
    // ---- T1 XCD swizzle: physical id p -> logical chunk (p%8)*cpx + p/8 ----
    int gx = gridDim.x, gy = gridDim.y;
    int wg = blockIdx.x + gx * (blockIdx.y + gy * blockIdx.z);
    int nwg = gx * gy * gridDim.z;
    wg = (wg & 7) * (nwg >> 3) + (wg >> 3);
    int z = wg / (gx * gy);
    int rem = wg - z * (gx * gy);
    int by = rem / gx, bx = rem - by * gx;
    int m0 = by * 64, n0 = bx * 128;
    int tid = threadIdx.x;
    int lane = tid & 63, wv = tid >> 6;

    const u16* ag[2]; const u16* bg[4];
    u32 la[2], lb[4];
#pragma unroll
    for (int i = 0; i < 2; ++i) {
        int q = i * 256 + tid;
        int row = q >> 3, c = q & 7;
        ag[i] = A + aStr * z + (size_t)(m0 + row) * lda + (c ^ (row & 7)) * 8;
        la[i] = i * 2048 + wv * 512;
    }
#pragma unroll
    for (int i = 0; i < 4; ++i) {
        int q = i * 256 + tid;
        int row = q >> 3, c = q & 7;
        bg[i] = Bm + bStr * z + (size_t)(n0 + row) * ldb + (c ^ (row & 7)) * 8;
        lb[i] = 8192 + i * 2048 + wv * 512;
    }

    int mw = (wv >> 1) * 32, nw = (wv & 1) * 64;
    int lr = lane & 15, lq = lane >> 4;
    int sw = lr & 7;

    ffrag acc[2][4];
#pragma unroll
    for (int i = 0; i < 2; ++i)
#pragma unroll
        for (int j = 0; j < 4; ++j) acc[i][j] = (ffrag){0.f, 0.f, 0.f, 0.f};

    // prologue: stage k=0 into buf0
#pragma unroll
    for (int i = 0; i < 2; ++i) gload_lds16(ag[i], &lds[la[i]]);
#pragma unroll
    for (int i = 0; i < 4; ++i) gload_lds16(bg[i], &lds[lb[i]]);

    for (int k0 = 0; k0 < K; k0 += 64) {
        int cur = (k0 >> 6) & 1;
        if (k0 + 64 < K) {
            // prefetch next tile into other buffer (6 loads stay in flight)
#pragma unroll
            for (int i = 0; i < 2; ++i)
                gload_lds16(ag[i] + k0 + 64, &lds[((cur ^ 1) << 12) + la[i]]);
#pragma unroll
            for (int i = 0; i < 4; ++i)
                gload_lds16(bg[i] + k0 + 64, &lds[((cur ^ 1) << 13) + lb[i]]);
            asm volatile("s_waitcnt vmcnt(6)" ::: "memory");
        } else {
            asm volatile("s_waitcnt vmcnt(0)" ::: "memory");
        }
        asm volatile("s_barrier" ::: "memory");   // all waves: cur tile resident

        const u16* Ab = &lds[cur << 12];
        const u16* Bb = &lds[8192 + (cur << 13)];
#pragma unroll
        for (int h = 0; h < 2; ++h) {
            bfrag af[2], bf[4];
#pragma unroll
            for (int i = 0; i < 2; ++i)
                af[i] = *(const bfrag*)&Ab[(mw + i * 16 + lr) * 64 + ((h * 4 + lq) ^ sw) * 8];
#pragma unroll
            for (int j = 0; j < 4; ++j)
                bf[j] = *(const bfrag*)&Bb[(nw + j * 16 + lr) * 64 + ((h * 4 + lq) ^ sw) * 8];
#pragma unroll
            for (int i = 0; i < 2; ++i)
#pragma unroll
                for (int j = 0; j < 4; ++j)
                    acc[i][j] = __builtin_amdgcn_mfma_f32_16x16x32_bf16(af[i], bf[j], acc[i][j], 0, 0, 0);
        }
        // all waves done reading cur before next iter overwrites it
        asm volatile("s_waitcnt lgkmcnt(0)\ns_barrier" ::: "memory");
    }

    float* Cf = (float*)Cout + cStr * z;
    const float* resf = (const float*)res;
    const u16*   resb = (const u16*)res;
#pragma unroll
    for (int i = 0; i < 2; ++i) {
        int row = m0 + mw + i * 16 + lq * 4;
#pragma unroll
        for (int j = 0; j < 4; ++j) {
            int col = n0 + nw + j * 16 + lr;
            float bv = (EPI != 0) ? bias[col] : 0.f;
#pragma unroll
            for (int r = 0; r < 4; ++r) {
                float v = acc[i][j][r] + bv;
                size_t off = (size_t)(row + r) * N + col;
                if (EPI == 0) {
                    Cf[off] = v + resf[resStr * z + off];
                } else {
                    Cf[off] = v + b2f(resb[off]);
                }
            }
        }
    }
}

// ======================= bf16 MFMA GEMM: 128x128 tile ============================
// Same AITER-style vmcnt pipeline, 8 staging loads/tile -> vmcnt(8).
// T1 XCD swizzle. EPI=1 epilogue routes the C-tile through LDS so the bf16 output
// is written as 16B/lane coalesced streams instead of 32B scattered segments.
template <int EPI>
__global__ __launch_bounds__(256) void gemm128(
    const u16* __restrict__ A, const u16* __restrict__ Bm,
    const float* __restrict__ bias, const void* __restrict__ res,
    void* __restrict__ Cout, int K, int N, int lda, int ldb,
    size_t aStr, size_t bStr, size_t cStr, size_t resStr)
{
    // layout (u16 elems): A buf0 [0,8192) buf1 [8192,16384); B buf0 [16384,24576) buf1 [24576,32768)
    __shared__ __align__(16) u16 lds[32768];   // 64 KB
    // ---- T1 XCD swizzle ----
    int gx = gridDim.x, gy = gridDim.y;
    int wg = blockIdx.x + gx * (blockIdx.y + gy * blockIdx.z);
    int nwg = gx * gy * gridDim.z;
    wg = (wg & 7) * (nwg >> 3) + (wg >> 3);
    int z = wg / (gx * gy);
    int rem = wg - z * (gx * gy);
    int by = rem / gx, bx = rem - by * gx;
    int m0 = by * 128, n0 = bx * 128;
    int tid = threadIdx.x;
    int lane = tid & 63, wv = tid >> 6;

    const u16* ag[4]; const u16* bg[4];
    u32 la[4], lb[4];
#pragma unroll
    for (int i = 0; i < 4; ++i) {
        int q = i * 256 + tid;
        int row = q >> 3, c = q & 7;       // row in [0,128)
        ag[i] = A + aStr * z + (size_t)(m0 + row) * lda + (c ^ (row & 7)) * 8;
        la[i] = i * 2048 + wv * 512;
        bg[i] = Bm + bStr * z + (size_t)(n0 + row) * ldb + (c ^ (row & 7)) * 8;
        lb[i] = 16384 + i * 2048 + wv * 512;
    }

    int mw = (wv >> 1) * 64, nw = (wv & 1) * 64;
    int lr = lane & 15, lq = lane >> 4;
    int sw = lr & 7;

    ffrag acc[4][4];
#pragma unroll
    for (int i = 0; i < 4; ++i)
#pragma unroll
        for (int j = 0; j < 4; ++j) acc[i][j] = (ffrag){0.f, 0.f, 0.f, 0.f};

    // prologue: stage k=0 into buf0
#pragma unroll
    for (int i = 0; i < 4; ++i) gload_lds16(ag[i], &lds[la[i]]);
#pragma unroll
    for (int i = 0; i < 4; ++i) gload_lds16(bg[i], &lds[lb[i]]);

    for (int k0 = 0; k0 < K; k0 += 64) {
        int cur = (k0 >> 6) & 1;
        if (k0 + 64 < K) {
            // prefetch next tile into other buffer (8 loads stay in flight)
#pragma unroll
            for (int i = 0; i < 4; ++i)
                gload_lds16(ag[i] + k0 + 64, &lds[((cur ^ 1) << 13) + la[i]]);
#pragma unroll
            for (int i = 0; i < 4; ++i)
                gload_lds16(bg[i] + k0 + 64, &lds[((cur ^ 1) << 13) + lb[i]]);
            asm volatile("s_waitcnt vmcnt(8)" ::: "memory");
        } else {
            asm volatile("s_waitcnt vmcnt(0)" ::: "memory");
        }
        asm volatile("s_barrier" ::: "memory");   // all waves: cur tile resident

        const u16* Ab = &lds[cur << 13];
        const u16* Bb = &lds[16384 + (cur << 13)];
#pragma unroll
        for (int h = 0; h < 2; ++h) {
            bfrag af[4], bf[4];
#pragma unroll
            for (int i = 0; i < 4; ++i)
                af[i] = *(const bfrag*)&Ab[(mw + i * 16 + lr) * 64 + ((h * 4 + lq) ^ sw) * 8];
#pragma unroll
            for (int j = 0; j < 4; ++j)
                bf[j] = *(const bfrag*)&Bb[(nw + j * 16 + lr) * 64 + ((h * 4 + lq) ^ sw) * 8];
#pragma unroll
            for (int i = 0; i < 4; ++i)
#pragma unroll
                for (int j = 0; j < 4; ++j)
                    acc[i][j] = __builtin_amdgcn_mfma_f32_16x16x32_bf16(af[i], bf[j], acc[i][j], 0, 0, 0);
        }
        // all waves done reading cur before next iter overwrites it
        asm volatile("s_waitcnt lgkmcnt(0)\ns_barrier" ::: "memory");
    }

    float* Cf = (float*)Cout + cStr * z;
    u16*   Cb = (u16*)Cout + cStr * z;
    const float* resf = (const float*)res;
    const u16*   resb = (const u16*)res;
    if (EPI == 1) {
        // stage bf16 C-tile in LDS (row stride 136 u16 = 272B, 16B-aligned,
        // lq-groups land on disjoint bank sets), then stream out coalesced.
        u16* sb = lds;
#pragma unroll
        for (int i = 0; i < 4; ++i) {
            int rr = mw + i * 16 + lq * 4;
#pragma unroll
            for (int j = 0; j < 4; ++j) {
                int cc = nw + j * 16 + lr;
                float bv = bias[n0 + cc];
#pragma unroll
                for (int r = 0; r < 4; ++r)
                    sb[(rr + r) * 136 + cc] = f2b(gelu_cheap(acc[i][j][r] + bv));
            }
        }
        __syncthreads();
        u16* Crow = Cb + (size_t)m0 * N + n0;
#pragma unroll
        for (int t = 0; t < 8; ++t) {
            int q = t * 256 + tid;           // 2048 x 16B chunks
            int row = q >> 4, c16 = q & 15;
            *(uint4*)(Crow + (size_t)row * N + c16 * 8) =
                *(const uint4*)(sb + row * 136 + c16 * 8);
        }
    } else {
#pragma unroll
        for (int i = 0; i < 4; ++i) {
            int row = m0 + mw + i * 16 + lq * 4;
#pragma unroll
            for (int j = 0; j < 4; ++j) {
                int col = n0 + nw + j * 16 + lr;
                float bv = (EPI != 0) ? bias[col] : 0.f;
#pragma unroll
                for (int r = 0; r < 4; ++r) {
                    float v = acc[i][j][r] + bv;
                    size_t off = (size_t)(row + r) * N + col;
                    if (EPI == 0) {
                        Cf[off] = v + resf[resStr * z + off];
                    } else {
                        Cf[off] = v + b2f(resb[off]);
                    }
                }
            }
        }
    }
}

// ---------------- layernorm over D=512, one row per block ------------------------
// BF=true: write bf16, else fp32. SP=true: also emit si/sj = x.w1, x.w2 for NEXT
// layer's attention scores (x-row is already in registers -> saves a 16MB re-read).
template <bool BF, bool SP>
__global__ __launch_bounds__(256) void ln_kernel(
    const float* __restrict__ in, const float* __restrict__ g,
    const float* __restrict__ be, void* __restrict__ out,
    const float* __restrict__ aw, float* __restrict__ si, float* __restrict__ sj)
{
    int row = blockIdx.x;
    int tid = threadIdx.x;
    const float2* rp = (const float2*)(in + (size_t)row * DD);
    float2 v = rp[tid];
    float s  = v.x + v.y;
    float ss = v.x * v.x + v.y * v.y;
#pragma unroll
    for (int off = 32; off > 0; off >>= 1) {
        s  += __shfl_xor(s, off);
        ss += __shfl_xor(ss, off);
    }
    __shared__ float sh[8];
    int wave = tid >> 6, lane = tid & 63;
    if (lane == 0) { sh[wave] = s; sh[4 + wave] = ss; }
    __syncthreads();
    float S  = sh[0] + sh[1] + sh[2] + sh[3];
    float SS = sh[4] + sh[5] + sh[6] + sh[7];
    float mean = S * (1.f / DD);
    float var  = SS * (1.f / DD) - mean * mean;
    var = fmaxf(var, 0.f);
    float rs = rsqrtf(var + 1e-5f);
    float2 gv = ((const float2*)g)[tid];
    float2 bv = ((const float2*)be)[tid];
    float ox = (v.x - mean) * rs * gv.x + bv.x;
    float oy = (v.y - mean) * rs * gv.y + bv.y;
    if (BF) {
        u32 w = (u32)f2b(ox) | ((u32)f2b(oy) << 16);
        ((u32*)out)[(size_t)row * (DD / 2) + tid] = w;
    } else {
        float2 o; o.x = ox; o.y = oy;
        ((float2*)out)[(size_t)row * (DD / 2) + tid] = o;
    }
    if (SP) {
        float2 wa = ((const float2*)aw)[tid];
        float2 wb = ((const float2*)(aw + DD))[tid];
        float a = ox * wa.x + oy * wa.y;
        float c = ox * wb.x + oy * wb.y;
#pragma unroll
        for (int off = 32; off > 0; off >>= 1) {
            a += __shfl_xor(a, off);
            c += __shfl_xor(c, off);
        }
        __syncthreads();                 // sh reuse
        if (lane == 0) { sh[wave] = a; sh[4 + wave] = c; }
        __syncthreads();
        if (tid == 0) {
            si[row] = sh[0] + sh[1] + sh[2] + sh[3];
            sj[row] = sh[4] + sh[5] + sh[6] + sh[7];
        }
    }
}

extern "C" void kernel_launch(void* const* d_in, const int* in_sizes, int n_in,
                              void* d_out, int out_size, void* d_ws, size_t ws_size,
                              hipStream_t stream) {
    const float* nf     = (const float*)d_in[0];
    const int*   adj    = (const int*)d_in[1];
    const float* attn_w = (const float*)d_in[2];
    const float* attn_b = (const float*)d_in[3];
    const float* W1     = (const float*)d_in[4];
    const float* b1     = (const float*)d_in[5];
    const float* W2     = (const float*)d_in[6];
    const float* b2     = (const float*)d_in[7];
    const float* g1     = (const float*)d_in[8];
    const float* be1    = (const float*)d_in[9];
    const float* g2     = (const float*)d_in[10];
    const float* be2    = (const float*)d_in[11];
    float* out = (float*)d_out;

    char* wsb = (char*)d_ws;
    float* x_cur = (float*)(wsb);                      // 16 MB [0,16M)
    u16*   h_bf  = (u16*)(wsb + 16777216);             //  8 MB [16,24M)
    char*  scr   = wsb + 25165824;                     // 32 MB [24,56M)
    u16*   P     = (u16*)scr;                          //   [24,40M)
    float* hres  = (float*)(scr + 16777216);           //   [40,56M)
    u16*   mid   = (u16*)scr;                          //   [24,56M) after ln1 (P,hres dead)
    u16*   xT    = (u16*)(wsb + 58720256);             //  8 MB [56,64M)
    u16*   W1t   = (u16*)(wsb + 67108864);             //  6 MB [64,70M)
    u16*   W2t   = (u16*)(wsb + 73400320);             //  6 MB [70,76M)
    u64*   mask  = (u64*)(wsb + 79691776);             //  1 MB [76,77M)
    float* si    = (float*)(wsb + 80740352);           // 32 KB
    float* sj    = (float*)(wsb + 80773120);           // 32 KB

    // prep, 2 dispatches: {mask + layer-0 scores + nf->xT} and {both weight sets}
    prep_fused<<<6656, 256, 0, stream>>>(adj, mask, nf, attn_w, si, sj, xT);
    trans_w<<<dim3(64, 16, 6), 256, 0, stream>>>(W1, W2, W1t, W2t);

    for (int l = 0; l < 3; ++l) {
        const float* xin = (l == 0) ? nf : x_cur;
        if (l == 0) {
            softmax_p<<<1024, 256, 0, stream>>>(si, sj, attn_b, mask, P);
        } else {
            // fused: softmax (1024 blocks) + x_cur->xT transpose (4096 blocks)
            sm_xt_fused<<<5120, 256, 0, stream>>>(si, sj, attn_b + l, mask, P,
                                                  x_cur, xT);
        }
        // agg: hres[b] = P[b] @ x[b]^T + x[b]   (64x128 tiles, 512 blocks, K=1024)
        gemm64<0><<<dim3(4, 16, 8), 256, 0, stream>>>(
            P, xT, nullptr, xin, hres, 1024, 512, 1024, 1024,
            (size_t)NN * NN, (size_t)DD * NN, (size_t)NN * DD, (size_t)NN * DD);
        // ln1 -> bf16 h
        ln_kernel<true, false><<<8192, 256, 0, stream>>>(
            hres, g1 + (size_t)l * 512, be1 + (size_t)l * 512, h_bf, nullptr, nullptr, nullptr);
        // FFN1: mid = gelu(h @ W1 + b1)  (bf16 out; 128x128 tiles, 1024 blocks, K=512)
        gemm128<1><<<dim3(16, 64, 1), 256, 0, stream>>>(
            h_bf, W1t + (size_t)l * 1048576, b1 + (size_t)l * 2048, nullptr, mid,
            512, 2048, 512, 512, 0, 0, 0, 0);
        // FFN2: x_cur = mid @ W2 + b2 + h   (512 blocks, K=2048)
        gemm64<2><<<dim3(4, 128, 1), 256, 0, stream>>>(
            mid, W2t + (size_t)l * 1048576, b2 + (size_t)l * 512, h_bf, x_cur,
            2048, 512, 2048, 2048, 0, 0, 0, 0);
        if (l < 2) {
            ln_kernel<false, true><<<8192, 256, 0, stream>>>(
                x_cur, g2 + (size_t)l * 512, be2 + (size_t)l * 512, x_cur,
                attn_w + (size_t)(l + 1) * 1024, si, sj);
        } else {
            ln_kernel<false, false><<<8192, 256, 0, stream>>>(
                x_cur, g2 + (size_t)l * 512, be2 + (size_t)l * 512, out,
                nullptr, nullptr, nullptr);
        }
    }
}